// Round 10
// baseline (487.595 us; speedup 1.0000x reference)
//
#include <hip/hip_runtime.h>
#include <hip/hip_bf16.h>

typedef __bf16 bf16;
typedef __bf16 bf16x4 __attribute__((ext_vector_type(4)));
typedef __bf16 bf16x8 __attribute__((ext_vector_type(8)));
typedef float f32x4 __attribute__((ext_vector_type(4)));

constexpr int N_NODES  = 100000;
constexpr int N_EDGES  = 800000;
constexpr int N_GRAPHS = 512;
constexpr int D_IN  = 300;
constexpr int D_HID = 300;
constexpr int D_OUT = 128;
constexpr int KP    = 320;   // padded feature stride
constexpr int MT    = 128;   // GEMM M-tile rows
constexpr int NTILE = (N_NODES + MT - 1) / MT;   // 782
constexpr int NPAD  = NTILE * MT;                // 100096

#define AS1(p) ((const __attribute__((address_space(1))) void*)(p))
#define AS3(p) ((__attribute__((address_space(3))) void*)(p))

// ---------------- setup kernels ----------------

__global__ __launch_bounds__(256) void k_init(int* deg, float* gsum, int* cnt) {
  int i = blockIdx.x * 256 + threadIdx.x;
  if (i < N_NODES) deg[i] = 0;
  if (i < N_GRAPHS) { gsum[i] = 0.f; cnt[i] = 0; }
}

// 4 edges per thread, int4 loads
__global__ __launch_bounds__(256) void k_deg(const int* __restrict__ ei, int* __restrict__ deg) {
  int e4 = blockIdx.x * 256 + threadIdx.x;
  if (e4 < N_EDGES / 4) {
    int4 d4 = ((const int4*)(ei + N_EDGES))[e4];
    atomicAdd(&deg[d4.x], 1);
    atomicAdd(&deg[d4.y], 1);
    atomicAdd(&deg[d4.z], 1);
    atomicAdd(&deg[d4.w], 1);
  }
}

__global__ __launch_bounds__(256) void k_scan1(const int* __restrict__ deg, int* __restrict__ rp,
                                               int* __restrict__ part) {
  __shared__ int sm[256];
  int tid = threadIdx.x;
  int i = blockIdx.x * 256 + tid;
  int v = (i < N_NODES) ? deg[i] : 0;
  sm[tid] = v;
  __syncthreads();
  for (int off = 1; off < 256; off <<= 1) {
    int t = (tid >= off) ? sm[tid - off] : 0;
    __syncthreads();
    sm[tid] += t;
    __syncthreads();
  }
  if (i < N_NODES) rp[i] = sm[tid] - v;
  if (tid == 255) part[blockIdx.x] = sm[255];
}

__global__ __launch_bounds__(512) void k_scan2(int* part, int nb) {
  __shared__ int sm[512];
  int tid = threadIdx.x;
  int v = (tid < nb) ? part[tid] : 0;
  sm[tid] = v;
  __syncthreads();
  for (int off = 1; off < 512; off <<= 1) {
    int t = (tid >= off) ? sm[tid - off] : 0;
    __syncthreads();
    sm[tid] += t;
    __syncthreads();
  }
  if (tid < nb) part[tid] = sm[tid] - v;
}

// scan finalize + dinv fused
__global__ __launch_bounds__(256) void k_scan3(int* __restrict__ rp, const int* __restrict__ part,
                                               int* __restrict__ cur, const int* __restrict__ deg,
                                               float* __restrict__ dinv) {
  int i = blockIdx.x * 256 + threadIdx.x;
  if (i < N_NODES) {
    int r = rp[i] + part[blockIdx.x];
    rp[i] = r;
    cur[i] = r;
    dinv[i] = rsqrtf((float)(deg[i] + 1));   // +1 self loop
  }
  if (i == 0) rp[N_NODES] = N_EDGES;
}

// 4 edges per thread, int4 loads
__global__ __launch_bounds__(256) void k_fill(const int* __restrict__ ei, int* __restrict__ cur,
                                              int* __restrict__ col) {
  int e4 = blockIdx.x * 256 + threadIdx.x;
  if (e4 < N_EDGES / 4) {
    int4 s4 = ((const int4*)ei)[e4];
    int4 d4 = ((const int4*)(ei + N_EDGES))[e4];
    col[atomicAdd(&cur[d4.x], 1)] = s4.x;
    col[atomicAdd(&cur[d4.y], 1)] = s4.y;
    col[atomicAdd(&cur[d4.z], 1)] = s4.z;
    col[atomicAdd(&cur[d4.w], 1)] = s4.w;
  }
}

// ---------------- conversions ----------------

// Xs[v][k] = dinv[v] * x[v][k] as bf16, zero-padded to KP
__global__ __launch_bounds__(256) void k_conv_x(const float* __restrict__ x, const float* __restrict__ dinv,
                                                bf16* __restrict__ Xs) {
  int i = blockIdx.x * 256 + threadIdx.x;       // over N_NODES*80
  if (i >= N_NODES * (KP / 4)) return;
  int j = i % (KP / 4);
  int v = i / (KP / 4);
  float4 f = make_float4(0.f, 0.f, 0.f, 0.f);
  if (j < D_IN / 4) f = ((const float4*)(x + (size_t)v * D_IN))[j];
  float dv = dinv[v];
  bf16x4 o;
  o[0] = (bf16)(f.x * dv); o[1] = (bf16)(f.y * dv); o[2] = (bf16)(f.z * dv); o[3] = (bf16)(f.w * dv);
  *(bf16x4*)(Xs + (size_t)v * KP + j * 4) = o;
}

// Wt[n][k] = W[k][n], zero-padded to [KP][KP]
__global__ __launch_bounds__(256) void k_conv_w(const float* __restrict__ W, bf16* __restrict__ Wt,
                                                int Kin, int Nin) {
  int i = blockIdx.x * 256 + threadIdx.x;
  if (i >= KP * KP) return;
  int k = i % KP;
  int n = i / KP;
  float f = (k < Kin && n < Nin) ? W[k * Nin + n] : 0.f;
  Wt[i] = (bf16)f;
}

// ---------------- aggregation (pre-GEMM, bf16): out[v] = dinv[v]*(sum_nbr in[u] + in[v]) ----------------
// R4 form (VGPR 32, occ ~73%): lanes 0..39 own 8 cols; x4 unroll, 2 acc sets.

__global__ __launch_bounds__(256) void k_aggb(const bf16* __restrict__ in, const int* __restrict__ rp,
                                              const int* __restrict__ col, const float* __restrict__ dinv,
                                              bf16* __restrict__ out) {
  int w = threadIdx.x >> 6, l = threadIdx.x & 63;
  int v = blockIdx.x * 4 + w;
  if (v >= N_NODES) return;
  if (l >= 40) return;                         // 40 lanes x 8 cols = 320
  const size_t co = (size_t)8 * l;

  float A0[8], A1[8];
  {                                            // init with self row
    bf16x8 p = *(const bf16x8*)(in + (size_t)v * KP + co);
#pragma unroll
    for (int j = 0; j < 8; ++j) { A0[j] = (float)p[j]; A1[j] = 0.f; }
  }
  int s = rp[v], e = rp[v + 1];
  int i = s;
  for (; i + 4 <= e; i += 4) {
    int u0 = col[i], u1 = col[i + 1], u2 = col[i + 2], u3 = col[i + 3];
    bf16x8 p0 = *(const bf16x8*)(in + (size_t)u0 * KP + co);
    bf16x8 p1 = *(const bf16x8*)(in + (size_t)u1 * KP + co);
    bf16x8 p2 = *(const bf16x8*)(in + (size_t)u2 * KP + co);
    bf16x8 p3 = *(const bf16x8*)(in + (size_t)u3 * KP + co);
#pragma unroll
    for (int j = 0; j < 8; ++j) {
      A0[j] += (float)p0[j] + (float)p2[j];
      A1[j] += (float)p1[j] + (float)p3[j];
    }
  }
  for (; i + 2 <= e; i += 2) {
    int u0 = col[i], u1 = col[i + 1];
    bf16x8 p0 = *(const bf16x8*)(in + (size_t)u0 * KP + co);
    bf16x8 p1 = *(const bf16x8*)(in + (size_t)u1 * KP + co);
#pragma unroll
    for (int j = 0; j < 8; ++j) { A0[j] += (float)p0[j]; A1[j] += (float)p1[j]; }
  }
  if (i < e) {
    int u0 = col[i];
    bf16x8 p0 = *(const bf16x8*)(in + (size_t)u0 * KP + co);
#pragma unroll
    for (int j = 0; j < 8; ++j) A0[j] += (float)p0[j];
  }
  float dv = dinv[v];
  bf16x8 o;
#pragma unroll
  for (int j = 0; j < 8; ++j) o[j] = (bf16)((A0[j] + A1[j]) * dv);
  *(bf16x8*)(out + (size_t)v * KP + co) = o;
}

// ---------------- layer-3 post-GEMM aggregation ----------------
// T3: [NPAD][128] bf16. T3[u] = (H·W3)[u] = dinv[u]*(h2·W3)[u] — already gather-prescaled.
// sArr[v] = sum_d relu(dinv[v]*(sum_nbr T3[u] + T3[v])[d] + b3[d]) * Wm[d]

__global__ __launch_bounds__(256) void k_agg3(const bf16* __restrict__ T3, const int* __restrict__ rp,
                                              const int* __restrict__ col, const float* __restrict__ dinv,
                                              const float* __restrict__ bias, const float* __restrict__ Wm,
                                              float* __restrict__ sArr) {
  const int tid = threadIdx.x;
  const int c = tid & 15;                      // 16B chunk within row
  const int v = blockIdx.x * 16 + (tid >> 4);  // grid is exactly N_NODES/16
  const size_t co = (size_t)8 * c;

  float A0[8], A1[8];
  {                                            // self row
    bf16x8 p = *(const bf16x8*)(T3 + (size_t)v * 128 + co);
#pragma unroll
    for (int j = 0; j < 8; ++j) { A0[j] = (float)p[j]; A1[j] = 0.f; }
  }
  int s = rp[v], e = rp[v + 1];
  int i = s;
  for (; i + 4 <= e; i += 4) {
    int u0 = col[i], u1 = col[i + 1], u2 = col[i + 2], u3 = col[i + 3];
    bf16x8 p0 = *(const bf16x8*)(T3 + (size_t)u0 * 128 + co);
    bf16x8 p1 = *(const bf16x8*)(T3 + (size_t)u1 * 128 + co);
    bf16x8 p2 = *(const bf16x8*)(T3 + (size_t)u2 * 128 + co);
    bf16x8 p3 = *(const bf16x8*)(T3 + (size_t)u3 * 128 + co);
#pragma unroll
    for (int j = 0; j < 8; ++j) {
      A0[j] += (float)p0[j] + (float)p2[j];
      A1[j] += (float)p1[j] + (float)p3[j];
    }
  }
  for (; i + 2 <= e; i += 2) {
    int u0 = col[i], u1 = col[i + 1];
    bf16x8 p0 = *(const bf16x8*)(T3 + (size_t)u0 * 128 + co);
    bf16x8 p1 = *(const bf16x8*)(T3 + (size_t)u1 * 128 + co);
#pragma unroll
    for (int j = 0; j < 8; ++j) { A0[j] += (float)p0[j]; A1[j] += (float)p1[j]; }
  }
  if (i < e) {
    bf16x8 p0 = *(const bf16x8*)(T3 + (size_t)col[i] * 128 + co);
#pragma unroll
    for (int j = 0; j < 8; ++j) A0[j] += (float)p0[j];
  }

  float dv = dinv[v];
  float sv = 0.f;
#pragma unroll
  for (int j = 0; j < 8; ++j) {
    int d = (int)co + j;
    float val = fmaxf((A0[j] + A1[j]) * dv + bias[d], 0.f);
    sv += val * Wm[d];
  }
#pragma unroll
  for (int m = 1; m < 16; m <<= 1) sv += __shfl_xor(sv, m);  // reduce within 16-lane group
  if (c == 0) sArr[v] = sv;
}

// ---------------- GEMM: A-DIRECT variant ----------------
// R9 journal: barrier drain (vmcnt(0) in __syncthreads) was gated by the A-tile staging
// (L3/cross-XCD latency); B is XCD-L2-resident after the first block. So: NO A LDS tile —
// each wave loads its A fragments straight global->VGPR (lane la reads 16 consecutive rows
// at one 32B k-window = one fully-used 64B line per row; A row feeds only its own C row so
// no cross-wave reuse is lost). Barrier now only drains B (5 gload_lds). LDS 40/16 KB.
// B LDS rows 128B, XOR-swizzled via pre-swizzled global source; un-swizzled on ds_read.
// EPI 0: H[row][c] = dinv[row]*relu(acc + bias[c])   (bf16, stride KP)
// EPI 1: T3[row][c] = acc                            (bf16, stride NP; input rows carry dinv)

template <int NP, int WM, int WN, int EPI>
__global__ __launch_bounds__(512, 4) void k_gemm(const bf16* __restrict__ A, const bf16* __restrict__ Bt,
                                                 const float* __restrict__ dinv, const float* __restrict__ bias,
                                                 bf16* __restrict__ H) {
  constexpr int WROWS = MT / WM;
  constexpr int MI    = WROWS / 16;
  constexpr int WCOLS = NP / WN;
  constexpr int NC    = WCOLS / 16;
  constexpr int NB_B  = NP / 64;
  __shared__ __attribute__((aligned(16))) char sB[NP * 128];   // 40/16 KB (B only)

  const int tid = threadIdx.x;
  const int w = tid >> 6, l = tid & 63;
  const int wm = w / WN, wn = w % WN;
  const int m0 = blockIdx.x * MT;

  const int sr  = tid >> 3;                      // staging row 0..63 per 64-row group
  const int ssw = ((tid & 7) << 4) ^ ((sr & 7) << 4);
  const char* Bb = (const char*)Bt;

  const int la = l & 15, q = l >> 4;
  const int msk = (la & 7) << 4;                 // read-side swizzle

  // A-direct base: row = m0 + wm*WROWS + mi*16 + la, elem col = kh*64 + ks*32 + q*8
  const bf16* Abase = A + (size_t)(m0 + wm * WROWS + la) * KP + q * 8;

  f32x4 acc[MI][NC] = {};

  for (int kh = 0; kh < 5; ++kh) {
#pragma unroll
    for (int i = 0; i < NB_B; ++i) {
      const char* src = Bb + (size_t)(i * 64 + sr) * 640 + kh * 128 + ssw;
      __builtin_amdgcn_global_load_lds(AS1(src), AS3(sB + i * 8192 + w * 1024), 16, 0, 0);
    }
    __syncthreads();                             // drains B staging only (no A in LDS)

#pragma unroll
    for (int ks = 0; ks < 2; ++ks) {
      bf16x8 af[MI];
#pragma unroll
      for (int mi = 0; mi < MI; ++mi)
        af[mi] = *(const bf16x8*)(Abase + (size_t)(mi * 16) * KP + kh * 64 + ks * 32);
      const int cb = (ks * 64 + q * 16) ^ msk;
#pragma unroll
      for (int nc = 0; nc < NC; ++nc) {
        int rb = wn * WCOLS + nc * 16 + la;
        bf16x8 bfr = *(const bf16x8*)(sB + rb * 128 + cb);
#pragma unroll
        for (int mi = 0; mi < MI; ++mi)
          acc[mi][nc] = __builtin_amdgcn_mfma_f32_16x16x32_bf16(af[mi], bfr, acc[mi][nc], 0, 0, 0);
      }
    }
    __syncthreads();                             // readers done before next B overwrite
  }

  // C/D layout: col = lane&15, row = (lane>>4)*4 + reg
  const int rbase = m0 + wm * WROWS + q * 4;
  if (EPI == 0) {
    float bc[NC];
#pragma unroll
    for (int nc = 0; nc < NC; ++nc) {
      int c = wn * WCOLS + nc * 16 + la;
      bc[nc] = (c < D_HID) ? bias[c] : 0.f;      // pad cols: acc=0, bias=0 -> stores 0
    }
#pragma unroll
    for (int mi = 0; mi < MI; ++mi) {
#pragma unroll
      for (int r = 0; r < 4; ++r) {
        int row = rbase + mi * 16 + r;
        if (row < N_NODES) {
          float dv = dinv[row];
#pragma unroll
          for (int nc = 0; nc < NC; ++nc) {
            int c = wn * WCOLS + nc * 16 + la;
            H[(size_t)row * KP + c] = (bf16)(fmaxf(acc[mi][nc][r] + bc[nc], 0.f) * dv);
          }
        }
      }
    }
  } else {
#pragma unroll
    for (int mi = 0; mi < MI; ++mi) {
#pragma unroll
      for (int r = 0; r < 4; ++r) {
        int row = rbase + mi * 16 + r;
        if (row < N_NODES) {
#pragma unroll
          for (int nc = 0; nc < NC; ++nc) {
            int c = wn * WCOLS + nc * 16 + la;
            H[(size_t)row * NP + c] = (bf16)acc[mi][nc][r];   // NO dinv: input rows already scaled
          }
        }
      }
    }
  }
}

// ---------------- pooled reduction ----------------

__global__ __launch_bounds__(256) void k_gsum(const float* __restrict__ sArr, const int* __restrict__ batch,
                                              float* __restrict__ gsum, int* __restrict__ cnt) {
  __shared__ float lsum[N_GRAPHS];
  __shared__ int   lcnt[N_GRAPHS];
  int tid = threadIdx.x;
  lsum[tid] = 0.f; lsum[tid + 256] = 0.f;
  lcnt[tid] = 0;   lcnt[tid + 256] = 0;
  __syncthreads();
  int v = blockIdx.x * 256 + tid;
  if (v < N_NODES) {
    int b = batch[v];
    atomicAdd(&lsum[b], sArr[v]);
    atomicAdd(&lcnt[b], 1);
  }
  __syncthreads();
  // sorted batch -> nonzero slots confined to [g0, g1]
  int v0 = blockIdx.x * 256;
  int v1 = min(v0 + 255, N_NODES - 1);
  int g0 = batch[v0], g1 = batch[v1];
  for (int g = g0 + tid; g <= g1; g += 256) {
    int c = lcnt[g];
    if (c) { atomicAdd(&gsum[g], lsum[g]); atomicAdd(&cnt[g], c); }
  }
}

__global__ __launch_bounds__(512) void k_final(const float* __restrict__ gsum, const int* __restrict__ cnt,
                                               const float* __restrict__ bm, float* __restrict__ out) {
  int g = blockIdx.x * 512 + threadIdx.x;
  if (g < N_GRAPHS) out[g] = gsum[g] / fmaxf((float)cnt[g], 1.f) + bm[0];
}

// ---------------- launch ----------------

extern "C" void kernel_launch(void* const* d_in, const int* in_sizes, int n_in,
                              void* d_out, int out_size, void* d_ws, size_t ws_size,
                              hipStream_t stream) {
  const float* x    = (const float*)d_in[0];
  const int*   ei   = (const int*)d_in[1];
  const int*   batch= (const int*)d_in[2];
  const float* W1   = (const float*)d_in[3];
  const float* b1   = (const float*)d_in[4];
  const float* W2   = (const float*)d_in[5];
  const float* b2   = (const float*)d_in[6];
  const float* W3   = (const float*)d_in[7];
  const float* b3   = (const float*)d_in[8];
  const float* Wm   = (const float*)d_in[9];
  const float* bm   = (const float*)d_in[10];
  float* out = (float*)d_out;

  char* ws = (char*)d_ws;
  size_t off = 0;
  auto alloc = [&](size_t bytes) {
    void* p = ws + off;
    off = (off + bytes + 255) & ~(size_t)255;
    return p;
  };
  bf16*  Xs   = (bf16*)alloc((size_t)NPAD * KP * sizeof(bf16));    // 64 MB; reused as H
  bf16*  Ab   = (bf16*)alloc((size_t)NPAD * KP * sizeof(bf16));    // 64 MB
  bf16*  T3   = (bf16*)alloc((size_t)NPAD * 128 * sizeof(bf16));   // 25.6 MB
  bf16*  Wt   = (bf16*)alloc((size_t)KP * KP * sizeof(bf16));
  int*   deg  = (int*)alloc((size_t)N_NODES * 4);
  float* dinv = (float*)alloc((size_t)N_NODES * 4);
  int*   rp   = (int*)alloc((size_t)(N_NODES + 1) * 4);
  int*   cur  = (int*)alloc((size_t)N_NODES * 4);
  int*   col  = (int*)alloc((size_t)N_EDGES * 4);
  int*   part = (int*)alloc(1024 * 4);
  float* sArr = (float*)alloc((size_t)N_NODES * 4);
  float* gsum = (float*)alloc((size_t)N_GRAPHS * 4);
  int*   cnt  = (int*)alloc((size_t)N_GRAPHS * 4);
  bf16*  H    = Xs;   // Xs dead after layer-1 agg

  int nbN = (N_NODES + 255) / 256;       // 391
  int nbE4 = (N_EDGES / 4 + 255) / 256;  // 782
  int nbA = (N_NODES + 3) / 4;           // 25000
  int nbW = (KP * KP + 255) / 256;

  k_init<<<nbN, 256, 0, stream>>>(deg, gsum, cnt);
  k_deg<<<nbE4, 256, 0, stream>>>(ei, deg);
  k_scan1<<<nbN, 256, 0, stream>>>(deg, rp, part);
  k_scan2<<<1, 512, 0, stream>>>(part, nbN);
  k_scan3<<<nbN, 256, 0, stream>>>(rp, part, cur, deg, dinv);
  k_fill<<<nbE4, 256, 0, stream>>>(ei, cur, col);
  k_conv_x<<<(N_NODES * (KP / 4) + 255) / 256, 256, 0, stream>>>(x, dinv, Xs);

  // layer 1: aggregate (bf16) -> GEMM (bias+relu+dinv)
  k_conv_w<<<nbW, 256, 0, stream>>>(W1, Wt, 300, 300);
  k_aggb<<<nbA, 256, 0, stream>>>(Xs, rp, col, dinv, Ab);
  k_gemm<KP, 2, 4, 0><<<NTILE, 512, 0, stream>>>(Ab, Wt, dinv, b1, H);
  // layer 2
  k_conv_w<<<nbW, 256, 0, stream>>>(W2, Wt, 300, 300);
  k_aggb<<<nbA, 256, 0, stream>>>(H, rp, col, dinv, Ab);
  k_gemm<KP, 2, 4, 0><<<NTILE, 512, 0, stream>>>(Ab, Wt, dinv, b2, H);
  // layer 3: GEMM first (128-wide; H rows already dinv-scaled), then aggregate + bias + relu + Wm-dot
  k_conv_w<<<nbW, 256, 0, stream>>>(W3, Wt, 300, 128);
  k_gemm<128, 8, 1, 1><<<NTILE, 512, 0, stream>>>(H, Wt, dinv, nullptr, T3);
  k_agg3<<<N_NODES / 16, 256, 0, stream>>>(T3, rp, col, dinv, b3, Wm, sArr);

  k_gsum<<<nbN, 256, 0, stream>>>(sArr, batch, gsum, cnt);
  k_final<<<1, 512, 0, stream>>>(gsum, cnt, bm, out);
}

// Round 11
// 455.543 us; speedup vs baseline: 1.0704x; 1.0704x over previous
//
#include <hip/hip_runtime.h>
#include <hip/hip_bf16.h>

typedef __bf16 bf16;
typedef __bf16 bf16x4 __attribute__((ext_vector_type(4)));
typedef __bf16 bf16x8 __attribute__((ext_vector_type(8)));
typedef float f32x4 __attribute__((ext_vector_type(4)));

constexpr int N_NODES  = 100000;
constexpr int N_EDGES  = 800000;
constexpr int N_GRAPHS = 512;
constexpr int D_IN  = 300;
constexpr int D_HID = 300;
constexpr int D_OUT = 128;
constexpr int KP    = 320;   // padded feature stride
constexpr int MT    = 128;   // GEMM M-tile rows
constexpr int NTILE = (N_NODES + MT - 1) / MT;   // 782
constexpr int NPAD  = NTILE * MT;                // 100096

#define AS1(p) ((const __attribute__((address_space(1))) void*)(p))
#define AS3(p) ((__attribute__((address_space(3))) void*)(p))

// ---------------- setup kernels ----------------

__global__ __launch_bounds__(256) void k_init(int* deg, float* gsum, int* cnt) {
  int i = blockIdx.x * 256 + threadIdx.x;
  if (i < N_NODES) deg[i] = 0;
  if (i < N_GRAPHS) { gsum[i] = 0.f; cnt[i] = 0; }
}

// 4 edges per thread, int4 loads
__global__ __launch_bounds__(256) void k_deg(const int* __restrict__ ei, int* __restrict__ deg) {
  int e4 = blockIdx.x * 256 + threadIdx.x;
  if (e4 < N_EDGES / 4) {
    int4 d4 = ((const int4*)(ei + N_EDGES))[e4];
    atomicAdd(&deg[d4.x], 1);
    atomicAdd(&deg[d4.y], 1);
    atomicAdd(&deg[d4.z], 1);
    atomicAdd(&deg[d4.w], 1);
  }
}

__global__ __launch_bounds__(256) void k_scan1(const int* __restrict__ deg, int* __restrict__ rp,
                                               int* __restrict__ part) {
  __shared__ int sm[256];
  int tid = threadIdx.x;
  int i = blockIdx.x * 256 + tid;
  int v = (i < N_NODES) ? deg[i] : 0;
  sm[tid] = v;
  __syncthreads();
  for (int off = 1; off < 256; off <<= 1) {
    int t = (tid >= off) ? sm[tid - off] : 0;
    __syncthreads();
    sm[tid] += t;
    __syncthreads();
  }
  if (i < N_NODES) rp[i] = sm[tid] - v;
  if (tid == 255) part[blockIdx.x] = sm[255];
}

__global__ __launch_bounds__(512) void k_scan2(int* part, int nb) {
  __shared__ int sm[512];
  int tid = threadIdx.x;
  int v = (tid < nb) ? part[tid] : 0;
  sm[tid] = v;
  __syncthreads();
  for (int off = 1; off < 512; off <<= 1) {
    int t = (tid >= off) ? sm[tid - off] : 0;
    __syncthreads();
    sm[tid] += t;
    __syncthreads();
  }
  if (tid < nb) part[tid] = sm[tid] - v;
}

// scan finalize + dinv fused
__global__ __launch_bounds__(256) void k_scan3(int* __restrict__ rp, const int* __restrict__ part,
                                               int* __restrict__ cur, const int* __restrict__ deg,
                                               float* __restrict__ dinv) {
  int i = blockIdx.x * 256 + threadIdx.x;
  if (i < N_NODES) {
    int r = rp[i] + part[blockIdx.x];
    rp[i] = r;
    cur[i] = r;
    dinv[i] = rsqrtf((float)(deg[i] + 1));   // +1 self loop
  }
  if (i == 0) rp[N_NODES] = N_EDGES;
}

// 4 edges per thread, int4 loads
__global__ __launch_bounds__(256) void k_fill(const int* __restrict__ ei, int* __restrict__ cur,
                                              int* __restrict__ col) {
  int e4 = blockIdx.x * 256 + threadIdx.x;
  if (e4 < N_EDGES / 4) {
    int4 s4 = ((const int4*)ei)[e4];
    int4 d4 = ((const int4*)(ei + N_EDGES))[e4];
    col[atomicAdd(&cur[d4.x], 1)] = s4.x;
    col[atomicAdd(&cur[d4.y], 1)] = s4.y;
    col[atomicAdd(&cur[d4.z], 1)] = s4.z;
    col[atomicAdd(&cur[d4.w], 1)] = s4.w;
  }
}

// ---------------- conversions ----------------

// Xs[v][k] = dinv[v] * x[v][k] as bf16, zero-padded to KP
__global__ __launch_bounds__(256) void k_conv_x(const float* __restrict__ x, const float* __restrict__ dinv,
                                                bf16* __restrict__ Xs) {
  int i = blockIdx.x * 256 + threadIdx.x;       // over N_NODES*80
  if (i >= N_NODES * (KP / 4)) return;
  int j = i % (KP / 4);
  int v = i / (KP / 4);
  float4 f = make_float4(0.f, 0.f, 0.f, 0.f);
  if (j < D_IN / 4) f = ((const float4*)(x + (size_t)v * D_IN))[j];
  float dv = dinv[v];
  bf16x4 o;
  o[0] = (bf16)(f.x * dv); o[1] = (bf16)(f.y * dv); o[2] = (bf16)(f.z * dv); o[3] = (bf16)(f.w * dv);
  *(bf16x4*)(Xs + (size_t)v * KP + j * 4) = o;
}

// Wt[n][k] = W[k][n], zero-padded to [KP][KP]
__global__ __launch_bounds__(256) void k_conv_w(const float* __restrict__ W, bf16* __restrict__ Wt,
                                                int Kin, int Nin) {
  int i = blockIdx.x * 256 + threadIdx.x;
  if (i >= KP * KP) return;
  int k = i % KP;
  int n = i / KP;
  float f = (k < Kin && n < Nin) ? W[k * Nin + n] : 0.f;
  Wt[i] = (bf16)f;
}

// ---------------- panel aggregation: out[v][C0..C0+CHUNKS*8) = dinv[v]*(sum_nbr in[u] + in[v]) ----------------
// Column-panel gather (R10 theory: per-pass working set 25.6/12.8 MB -> higher XCD-L2 hit rate
// than the 64 MB full-row gather). CHUNKS lanes per node, 256/CHUNKS nodes per block.
// Same 4-unroll / 2-acc-set order as before -> bit-identical sums per column.

template <int CHUNKS, int C0>
__global__ __launch_bounds__(256) void k_aggp(const bf16* __restrict__ in, const int* __restrict__ rp,
                                              const int* __restrict__ col, const float* __restrict__ dinv,
                                              bf16* __restrict__ out) {
  constexpr int NPB = 256 / CHUNKS;            // nodes per block
  const int tid = threadIdx.x;
  const int lc = tid & (CHUNKS - 1);
  const int g  = tid / CHUNKS;
  const int v = blockIdx.x * NPB + g;
  if (v >= N_NODES) return;
  const size_t co = (size_t)C0 + 8 * lc;

  float A0[8], A1[8];
  {                                            // self row
    bf16x8 p = *(const bf16x8*)(in + (size_t)v * KP + co);
#pragma unroll
    for (int j = 0; j < 8; ++j) { A0[j] = (float)p[j]; A1[j] = 0.f; }
  }
  int s = rp[v], e = rp[v + 1];
  int i = s;
  for (; i + 4 <= e; i += 4) {
    int u0 = col[i], u1 = col[i + 1], u2 = col[i + 2], u3 = col[i + 3];
    bf16x8 p0 = *(const bf16x8*)(in + (size_t)u0 * KP + co);
    bf16x8 p1 = *(const bf16x8*)(in + (size_t)u1 * KP + co);
    bf16x8 p2 = *(const bf16x8*)(in + (size_t)u2 * KP + co);
    bf16x8 p3 = *(const bf16x8*)(in + (size_t)u3 * KP + co);
#pragma unroll
    for (int j = 0; j < 8; ++j) {
      A0[j] += (float)p0[j] + (float)p2[j];
      A1[j] += (float)p1[j] + (float)p3[j];
    }
  }
  for (; i + 2 <= e; i += 2) {
    int u0 = col[i], u1 = col[i + 1];
    bf16x8 p0 = *(const bf16x8*)(in + (size_t)u0 * KP + co);
    bf16x8 p1 = *(const bf16x8*)(in + (size_t)u1 * KP + co);
#pragma unroll
    for (int j = 0; j < 8; ++j) { A0[j] += (float)p0[j]; A1[j] += (float)p1[j]; }
  }
  if (i < e) {
    bf16x8 p0 = *(const bf16x8*)(in + (size_t)col[i] * KP + co);
#pragma unroll
    for (int j = 0; j < 8; ++j) A0[j] += (float)p0[j];
  }
  float dv = dinv[v];
  bf16x8 o;
#pragma unroll
  for (int j = 0; j < 8; ++j) o[j] = (bf16)((A0[j] + A1[j]) * dv);
  *(bf16x8*)(out + (size_t)v * KP + co) = o;
}

// ---------------- layer-3 post-GEMM aggregation ----------------
// T3: [NPAD][128] bf16. T3[u] = (H·W3)[u] = dinv[u]*(h2·W3)[u] — already gather-prescaled.
// sArr[v] = sum_d relu(dinv[v]*(sum_nbr T3[u] + T3[v])[d] + b3[d]) * Wm[d]

__global__ __launch_bounds__(256) void k_agg3(const bf16* __restrict__ T3, const int* __restrict__ rp,
                                              const int* __restrict__ col, const float* __restrict__ dinv,
                                              const float* __restrict__ bias, const float* __restrict__ Wm,
                                              float* __restrict__ sArr) {
  const int tid = threadIdx.x;
  const int c = tid & 15;                      // 16B chunk within row
  const int v = blockIdx.x * 16 + (tid >> 4);  // grid is exactly N_NODES/16
  const size_t co = (size_t)8 * c;

  float A0[8], A1[8];
  {                                            // self row
    bf16x8 p = *(const bf16x8*)(T3 + (size_t)v * 128 + co);
#pragma unroll
    for (int j = 0; j < 8; ++j) { A0[j] = (float)p[j]; A1[j] = 0.f; }
  }
  int s = rp[v], e = rp[v + 1];
  int i = s;
  for (; i + 4 <= e; i += 4) {
    int u0 = col[i], u1 = col[i + 1], u2 = col[i + 2], u3 = col[i + 3];
    bf16x8 p0 = *(const bf16x8*)(T3 + (size_t)u0 * 128 + co);
    bf16x8 p1 = *(const bf16x8*)(T3 + (size_t)u1 * 128 + co);
    bf16x8 p2 = *(const bf16x8*)(T3 + (size_t)u2 * 128 + co);
    bf16x8 p3 = *(const bf16x8*)(T3 + (size_t)u3 * 128 + co);
#pragma unroll
    for (int j = 0; j < 8; ++j) {
      A0[j] += (float)p0[j] + (float)p2[j];
      A1[j] += (float)p1[j] + (float)p3[j];
    }
  }
  for (; i + 2 <= e; i += 2) {
    int u0 = col[i], u1 = col[i + 1];
    bf16x8 p0 = *(const bf16x8*)(T3 + (size_t)u0 * 128 + co);
    bf16x8 p1 = *(const bf16x8*)(T3 + (size_t)u1 * 128 + co);
#pragma unroll
    for (int j = 0; j < 8; ++j) { A0[j] += (float)p0[j]; A1[j] += (float)p1[j]; }
  }
  if (i < e) {
    bf16x8 p0 = *(const bf16x8*)(T3 + (size_t)col[i] * 128 + co);
#pragma unroll
    for (int j = 0; j < 8; ++j) A0[j] += (float)p0[j];
  }

  float dv = dinv[v];
  float sv = 0.f;
#pragma unroll
  for (int j = 0; j < 8; ++j) {
    int d = (int)co + j;
    float val = fmaxf((A0[j] + A1[j]) * dv + bias[d], 0.f);
    sv += val * Wm[d];
  }
#pragma unroll
  for (int m = 1; m < 16; m <<= 1) sv += __shfl_xor(sv, m);  // reduce within 16-lane group
  if (c == 0) sArr[v] = sv;
}

// ---------------- GEMM (R9 structure — the proven local optimum) ----------------
// R8 journal: BK=32 dbuf pipeline +40us (barrier drains vmcnt(0) anyway).
// R10 journal: A-direct (no A LDS) +43us (A latency lands on MFMA dep chain).
// Keep: A+B staged via global_load_lds, K in 5x64 chunks, 2 barriers/chunk, 8 waves.
// LDS rows 128B, XOR-swizzled via pre-swizzled GLOBAL source; un-swizzled on ds_read.
// EPI 0: H[row][c] = dinv[row]*relu(acc + bias[c])   (bf16, stride KP)
// EPI 1: T3[row][c] = acc                            (bf16, stride NP; input rows carry dinv)

template <int NP, int WM, int WN, int EPI>
__global__ __launch_bounds__(512, 4) void k_gemm(const bf16* __restrict__ A, const bf16* __restrict__ Bt,
                                                 const float* __restrict__ dinv, const float* __restrict__ bias,
                                                 bf16* __restrict__ H) {
  constexpr int WROWS = MT / WM;
  constexpr int MI    = WROWS / 16;
  constexpr int WCOLS = NP / WN;
  constexpr int NC    = WCOLS / 16;
  constexpr int NB_B  = NP / 64;
  __shared__ __attribute__((aligned(16))) char sA[MT * 128];   // 16 KB
  __shared__ __attribute__((aligned(16))) char sB[NP * 128];   // 40/16 KB

  const int tid = threadIdx.x;
  const int w = tid >> 6, l = tid & 63;
  const int wm = w / WN, wn = w % WN;
  const int m0 = blockIdx.x * MT;

  const int sr  = tid >> 3;                      // staging row 0..63 per 64-row group
  const int ssw = ((tid & 7) << 4) ^ ((sr & 7) << 4);
  const char* Ab = (const char*)A;
  const char* Bb = (const char*)Bt;

  const int la = l & 15, q = l >> 4;
  const int msk = (la & 7) << 4;                 // read-side swizzle

  f32x4 acc[MI][NC] = {};

  for (int kh = 0; kh < 5; ++kh) {
#pragma unroll
    for (int i = 0; i < 2; ++i) {
      const char* src = Ab + (size_t)(m0 + i * 64 + sr) * 640 + kh * 128 + ssw;
      __builtin_amdgcn_global_load_lds(AS1(src), AS3(sA + i * 8192 + w * 1024), 16, 0, 0);
    }
#pragma unroll
    for (int i = 0; i < NB_B; ++i) {
      const char* src = Bb + (size_t)(i * 64 + sr) * 640 + kh * 128 + ssw;
      __builtin_amdgcn_global_load_lds(AS1(src), AS3(sB + i * 8192 + w * 1024), 16, 0, 0);
    }
    __syncthreads();

#pragma unroll
    for (int ks = 0; ks < 2; ++ks) {
      const int cb = (ks * 64 + q * 16) ^ msk;
      bf16x8 af[MI];
#pragma unroll
      for (int mi = 0; mi < MI; ++mi) {
        int r = wm * WROWS + mi * 16 + la;
        af[mi] = *(const bf16x8*)(sA + r * 128 + cb);
      }
#pragma unroll
      for (int nc = 0; nc < NC; ++nc) {
        int rb = wn * WCOLS + nc * 16 + la;
        bf16x8 bfr = *(const bf16x8*)(sB + rb * 128 + cb);
#pragma unroll
        for (int mi = 0; mi < MI; ++mi)
          acc[mi][nc] = __builtin_amdgcn_mfma_f32_16x16x32_bf16(af[mi], bfr, acc[mi][nc], 0, 0, 0);
      }
    }
    __syncthreads();
  }

  // C/D layout: col = lane&15, row = (lane>>4)*4 + reg
  const int rbase = m0 + wm * WROWS + q * 4;
  if (EPI == 0) {
    float bc[NC];
#pragma unroll
    for (int nc = 0; nc < NC; ++nc) {
      int c = wn * WCOLS + nc * 16 + la;
      bc[nc] = (c < D_HID) ? bias[c] : 0.f;      // pad cols: acc=0, bias=0 -> stores 0
    }
#pragma unroll
    for (int mi = 0; mi < MI; ++mi) {
#pragma unroll
      for (int r = 0; r < 4; ++r) {
        int row = rbase + mi * 16 + r;
        if (row < N_NODES) {
          float dv = dinv[row];
#pragma unroll
          for (int nc = 0; nc < NC; ++nc) {
            int c = wn * WCOLS + nc * 16 + la;
            H[(size_t)row * KP + c] = (bf16)(fmaxf(acc[mi][nc][r] + bc[nc], 0.f) * dv);
          }
        }
      }
    }
  } else {
#pragma unroll
    for (int mi = 0; mi < MI; ++mi) {
#pragma unroll
      for (int r = 0; r < 4; ++r) {
        int row = rbase + mi * 16 + r;
        if (row < N_NODES) {
#pragma unroll
          for (int nc = 0; nc < NC; ++nc) {
            int c = wn * WCOLS + nc * 16 + la;
            H[(size_t)row * NP + c] = (bf16)acc[mi][nc][r];   // NO dinv: input rows already scaled
          }
        }
      }
    }
  }
}

// ---------------- pooled reduction ----------------

__global__ __launch_bounds__(256) void k_gsum(const float* __restrict__ sArr, const int* __restrict__ batch,
                                              float* __restrict__ gsum, int* __restrict__ cnt) {
  __shared__ float lsum[N_GRAPHS];
  __shared__ int   lcnt[N_GRAPHS];
  int tid = threadIdx.x;
  lsum[tid] = 0.f; lsum[tid + 256] = 0.f;
  lcnt[tid] = 0;   lcnt[tid + 256] = 0;
  __syncthreads();
  int v = blockIdx.x * 256 + tid;
  if (v < N_NODES) {
    int b = batch[v];
    atomicAdd(&lsum[b], sArr[v]);
    atomicAdd(&lcnt[b], 1);
  }
  __syncthreads();
  // sorted batch -> nonzero slots confined to [g0, g1]
  int v0 = blockIdx.x * 256;
  int v1 = min(v0 + 255, N_NODES - 1);
  int g0 = batch[v0], g1 = batch[v1];
  for (int g = g0 + tid; g <= g1; g += 256) {
    int c = lcnt[g];
    if (c) { atomicAdd(&gsum[g], lsum[g]); atomicAdd(&cnt[g], c); }
  }
}

__global__ __launch_bounds__(512) void k_final(const float* __restrict__ gsum, const int* __restrict__ cnt,
                                               const float* __restrict__ bm, float* __restrict__ out) {
  int g = blockIdx.x * 512 + threadIdx.x;
  if (g < N_GRAPHS) out[g] = gsum[g] / fmaxf((float)cnt[g], 1.f) + bm[0];
}

// ---------------- launch ----------------

extern "C" void kernel_launch(void* const* d_in, const int* in_sizes, int n_in,
                              void* d_out, int out_size, void* d_ws, size_t ws_size,
                              hipStream_t stream) {
  const float* x    = (const float*)d_in[0];
  const int*   ei   = (const int*)d_in[1];
  const int*   batch= (const int*)d_in[2];
  const float* W1   = (const float*)d_in[3];
  const float* b1   = (const float*)d_in[4];
  const float* W2   = (const float*)d_in[5];
  const float* b2   = (const float*)d_in[6];
  const float* W3   = (const float*)d_in[7];
  const float* b3   = (const float*)d_in[8];
  const float* Wm   = (const float*)d_in[9];
  const float* bm   = (const float*)d_in[10];
  float* out = (float*)d_out;

  char* ws = (char*)d_ws;
  size_t off = 0;
  auto alloc = [&](size_t bytes) {
    void* p = ws + off;
    off = (off + bytes + 255) & ~(size_t)255;
    return p;
  };
  bf16*  Xs   = (bf16*)alloc((size_t)NPAD * KP * sizeof(bf16));    // 64 MB; reused as H
  bf16*  Ab   = (bf16*)alloc((size_t)NPAD * KP * sizeof(bf16));    // 64 MB
  bf16*  T3   = (bf16*)alloc((size_t)NPAD * 128 * sizeof(bf16));   // 25.6 MB
  bf16*  Wt   = (bf16*)alloc((size_t)KP * KP * sizeof(bf16));
  int*   deg  = (int*)alloc((size_t)N_NODES * 4);
  float* dinv = (float*)alloc((size_t)N_NODES * 4);
  int*   rp   = (int*)alloc((size_t)(N_NODES + 1) * 4);
  int*   cur  = (int*)alloc((size_t)N_NODES * 4);
  int*   col  = (int*)alloc((size_t)N_EDGES * 4);
  int*   part = (int*)alloc(1024 * 4);
  float* sArr = (float*)alloc((size_t)N_NODES * 4);
  float* gsum = (float*)alloc((size_t)N_GRAPHS * 4);
  int*   cnt  = (int*)alloc((size_t)N_GRAPHS * 4);
  bf16*  H    = Xs;   // Xs dead after layer-1 agg

  int nbN = (N_NODES + 255) / 256;       // 391
  int nbE4 = (N_EDGES / 4 + 255) / 256;  // 782
  int nbP16 = (N_NODES + 15) / 16;       // 6250 (16 nodes/block, 16 lanes/node)
  int nbP8  = (N_NODES + 31) / 32;       // 3125 (32 nodes/block, 8 lanes/node)
  int nbW = (KP * KP + 255) / 256;

  k_init<<<nbN, 256, 0, stream>>>(deg, gsum, cnt);
  k_deg<<<nbE4, 256, 0, stream>>>(ei, deg);
  k_scan1<<<nbN, 256, 0, stream>>>(deg, rp, part);
  k_scan2<<<1, 512, 0, stream>>>(part, nbN);
  k_scan3<<<nbN, 256, 0, stream>>>(rp, part, cur, deg, dinv);
  k_fill<<<nbE4, 256, 0, stream>>>(ei, cur, col);
  k_conv_x<<<(N_NODES * (KP / 4) + 255) / 256, 256, 0, stream>>>(x, dinv, Xs);

  // layer 1: panel aggregation (bf16) -> GEMM (bias+relu+dinv)
  k_conv_w<<<nbW, 256, 0, stream>>>(W1, Wt, 300, 300);
  k_aggp<16, 0  ><<<nbP16, 256, 0, stream>>>(Xs, rp, col, dinv, Ab);
  k_aggp<16, 128><<<nbP16, 256, 0, stream>>>(Xs, rp, col, dinv, Ab);
  k_aggp<8,  256><<<nbP8,  256, 0, stream>>>(Xs, rp, col, dinv, Ab);
  k_gemm<KP, 2, 4, 0><<<NTILE, 512, 0, stream>>>(Ab, Wt, dinv, b1, H);
  // layer 2
  k_conv_w<<<nbW, 256, 0, stream>>>(W2, Wt, 300, 300);
  k_aggp<16, 0  ><<<nbP16, 256, 0, stream>>>(H, rp, col, dinv, Ab);
  k_aggp<16, 128><<<nbP16, 256, 0, stream>>>(H, rp, col, dinv, Ab);
  k_aggp<8,  256><<<nbP8,  256, 0, stream>>>(H, rp, col, dinv, Ab);
  k_gemm<KP, 2, 4, 0><<<NTILE, 512, 0, stream>>>(Ab, Wt, dinv, b2, H);
  // layer 3: GEMM first (128-wide; H rows already dinv-scaled), then aggregate + bias + relu + Wm-dot
  k_conv_w<<<nbW, 256, 0, stream>>>(W3, Wt, 300, 128);
  k_gemm<128, 8, 1, 1><<<NTILE, 512, 0, stream>>>(H, Wt, dinv, nullptr, T3);
  k_agg3<<<N_NODES / 16, 256, 0, stream>>>(T3, rp, col, dinv, b3, Wm, sArr);

  k_gsum<<<nbN, 256, 0, stream>>>(sArr, batch, gsum, cnt);
  k_final<<<1, 512, 0, stream>>>(gsum, cnt, bm, out);
}

// Round 12
// 436.558 us; speedup vs baseline: 1.1169x; 1.0435x over previous
//
#include <hip/hip_runtime.h>
#include <hip/hip_bf16.h>

typedef __bf16 bf16;
typedef __bf16 bf16x4 __attribute__((ext_vector_type(4)));
typedef __bf16 bf16x8 __attribute__((ext_vector_type(8)));
typedef float f32x4 __attribute__((ext_vector_type(4)));

constexpr int N_NODES  = 100000;
constexpr int N_EDGES  = 800000;
constexpr int N_GRAPHS = 512;
constexpr int D_IN  = 300;
constexpr int D_HID = 300;
constexpr int D_OUT = 128;
constexpr int KP    = 320;   // padded feature stride
constexpr int MT    = 128;   // GEMM M-tile rows
constexpr int NTILE = (N_NODES + MT - 1) / MT;   // 782
constexpr int NPAD  = NTILE * MT;                // 100096

#define AS1(p) ((const __attribute__((address_space(1))) void*)(p))
#define AS3(p) ((__attribute__((address_space(3))) void*)(p))

// ---------------- setup kernels ----------------

__global__ __launch_bounds__(256) void k_init(int* deg, float* gsum, int* cnt) {
  int i = blockIdx.x * 256 + threadIdx.x;
  if (i < N_NODES) deg[i] = 0;
  if (i < N_GRAPHS) { gsum[i] = 0.f; cnt[i] = 0; }
}

// 4 edges per thread, int4 loads
__global__ __launch_bounds__(256) void k_deg(const int* __restrict__ ei, int* __restrict__ deg) {
  int e4 = blockIdx.x * 256 + threadIdx.x;
  if (e4 < N_EDGES / 4) {
    int4 d4 = ((const int4*)(ei + N_EDGES))[e4];
    atomicAdd(&deg[d4.x], 1);
    atomicAdd(&deg[d4.y], 1);
    atomicAdd(&deg[d4.z], 1);
    atomicAdd(&deg[d4.w], 1);
  }
}

__global__ __launch_bounds__(256) void k_scan1(const int* __restrict__ deg, int* __restrict__ rp,
                                               int* __restrict__ part) {
  __shared__ int sm[256];
  int tid = threadIdx.x;
  int i = blockIdx.x * 256 + tid;
  int v = (i < N_NODES) ? deg[i] : 0;
  sm[tid] = v;
  __syncthreads();
  for (int off = 1; off < 256; off <<= 1) {
    int t = (tid >= off) ? sm[tid - off] : 0;
    __syncthreads();
    sm[tid] += t;
    __syncthreads();
  }
  if (i < N_NODES) rp[i] = sm[tid] - v;
  if (tid == 255) part[blockIdx.x] = sm[255];
}

__global__ __launch_bounds__(512) void k_scan2(int* part, int nb) {
  __shared__ int sm[512];
  int tid = threadIdx.x;
  int v = (tid < nb) ? part[tid] : 0;
  sm[tid] = v;
  __syncthreads();
  for (int off = 1; off < 512; off <<= 1) {
    int t = (tid >= off) ? sm[tid - off] : 0;
    __syncthreads();
    sm[tid] += t;
    __syncthreads();
  }
  if (tid < nb) part[tid] = sm[tid] - v;
}

// scan finalize + dinv fused
__global__ __launch_bounds__(256) void k_scan3(int* __restrict__ rp, const int* __restrict__ part,
                                               int* __restrict__ cur, const int* __restrict__ deg,
                                               float* __restrict__ dinv) {
  int i = blockIdx.x * 256 + threadIdx.x;
  if (i < N_NODES) {
    int r = rp[i] + part[blockIdx.x];
    rp[i] = r;
    cur[i] = r;
    dinv[i] = rsqrtf((float)(deg[i] + 1));   // +1 self loop
  }
  if (i == 0) rp[N_NODES] = N_EDGES;
}

// 4 edges per thread, int4 loads
__global__ __launch_bounds__(256) void k_fill(const int* __restrict__ ei, int* __restrict__ cur,
                                              int* __restrict__ col) {
  int e4 = blockIdx.x * 256 + threadIdx.x;
  if (e4 < N_EDGES / 4) {
    int4 s4 = ((const int4*)ei)[e4];
    int4 d4 = ((const int4*)(ei + N_EDGES))[e4];
    col[atomicAdd(&cur[d4.x], 1)] = s4.x;
    col[atomicAdd(&cur[d4.y], 1)] = s4.y;
    col[atomicAdd(&cur[d4.z], 1)] = s4.z;
    col[atomicAdd(&cur[d4.w], 1)] = s4.w;
  }
}

// ---------------- conversions ----------------

// Xs[v][k] = dinv[v] * x[v][k] as bf16, zero-padded to KP
__global__ __launch_bounds__(256) void k_conv_x(const float* __restrict__ x, const float* __restrict__ dinv,
                                                bf16* __restrict__ Xs) {
  int i = blockIdx.x * 256 + threadIdx.x;       // over N_NODES*80
  if (i >= N_NODES * (KP / 4)) return;
  int j = i % (KP / 4);
  int v = i / (KP / 4);
  float4 f = make_float4(0.f, 0.f, 0.f, 0.f);
  if (j < D_IN / 4) f = ((const float4*)(x + (size_t)v * D_IN))[j];
  float dv = dinv[v];
  bf16x4 o;
  o[0] = (bf16)(f.x * dv); o[1] = (bf16)(f.y * dv); o[2] = (bf16)(f.z * dv); o[3] = (bf16)(f.w * dv);
  *(bf16x4*)(Xs + (size_t)v * KP + j * 4) = o;
}

// All three weights transposed+padded in ONE dispatch: Wt[w][n][k] = W_w[k][n]
__global__ __launch_bounds__(256) void k_conv_w_all(const float* __restrict__ W1, const float* __restrict__ W2,
                                                    const float* __restrict__ W3, bf16* __restrict__ Wt) {
  int i = blockIdx.x * 256 + threadIdx.x;
  if (i >= 3 * KP * KP) return;
  int w = i / (KP * KP);
  int r = i % (KP * KP);
  int k = r % KP;
  int n = r / KP;
  float f = 0.f;
  if (w == 0)      { if (k < 300 && n < 300) f = W1[k * 300 + n]; }
  else if (w == 1) { if (k < 300 && n < 300) f = W2[k * 300 + n]; }
  else             { if (k < 300 && n < 128) f = W3[k * 128 + n]; }
  Wt[i] = (bf16)f;
}

// ---------------- aggregation (pre-GEMM, bf16): out[v] = dinv[v]*(sum_nbr in[u] + in[v]) ----------------
// R4 form (VGPR 32, occ ~73%): lanes 0..39 own 8 cols; x4 unroll, 2 acc sets.
// R11 journal: column-panel split (3 passes) = +10us — panels can't beat the 4MB/XCD L2 with
// random rows; this full-row form is at the L3-fabric roofline (~84us, 272MB L2-miss, ~4TB/s).

__global__ __launch_bounds__(256) void k_aggb(const bf16* __restrict__ in, const int* __restrict__ rp,
                                              const int* __restrict__ col, const float* __restrict__ dinv,
                                              bf16* __restrict__ out) {
  int w = threadIdx.x >> 6, l = threadIdx.x & 63;
  int v = blockIdx.x * 4 + w;
  if (v >= N_NODES) return;
  if (l >= 40) return;                         // 40 lanes x 8 cols = 320
  const size_t co = (size_t)8 * l;

  float A0[8], A1[8];
  {                                            // init with self row
    bf16x8 p = *(const bf16x8*)(in + (size_t)v * KP + co);
#pragma unroll
    for (int j = 0; j < 8; ++j) { A0[j] = (float)p[j]; A1[j] = 0.f; }
  }
  int s = rp[v], e = rp[v + 1];
  int i = s;
  for (; i + 4 <= e; i += 4) {
    int u0 = col[i], u1 = col[i + 1], u2 = col[i + 2], u3 = col[i + 3];
    bf16x8 p0 = *(const bf16x8*)(in + (size_t)u0 * KP + co);
    bf16x8 p1 = *(const bf16x8*)(in + (size_t)u1 * KP + co);
    bf16x8 p2 = *(const bf16x8*)(in + (size_t)u2 * KP + co);
    bf16x8 p3 = *(const bf16x8*)(in + (size_t)u3 * KP + co);
#pragma unroll
    for (int j = 0; j < 8; ++j) {
      A0[j] += (float)p0[j] + (float)p2[j];
      A1[j] += (float)p1[j] + (float)p3[j];
    }
  }
  for (; i + 2 <= e; i += 2) {
    int u0 = col[i], u1 = col[i + 1];
    bf16x8 p0 = *(const bf16x8*)(in + (size_t)u0 * KP + co);
    bf16x8 p1 = *(const bf16x8*)(in + (size_t)u1 * KP + co);
#pragma unroll
    for (int j = 0; j < 8; ++j) { A0[j] += (float)p0[j]; A1[j] += (float)p1[j]; }
  }
  if (i < e) {
    int u0 = col[i];
    bf16x8 p0 = *(const bf16x8*)(in + (size_t)u0 * KP + co);
#pragma unroll
    for (int j = 0; j < 8; ++j) A0[j] += (float)p0[j];
  }
  float dv = dinv[v];
  bf16x8 o;
#pragma unroll
  for (int j = 0; j < 8; ++j) o[j] = (bf16)((A0[j] + A1[j]) * dv);
  *(bf16x8*)(out + (size_t)v * KP + co) = o;
}

// ---------------- layer-3 post-GEMM aggregation ----------------
// T3: [NPAD][128] bf16. T3[u] = (H·W3)[u] = dinv[u]*(h2·W3)[u] — already gather-prescaled.
// sArr[v] = sum_d relu(dinv[v]*(sum_nbr T3[u] + T3[v])[d] + b3[d]) * Wm[d]

__global__ __launch_bounds__(256) void k_agg3(const bf16* __restrict__ T3, const int* __restrict__ rp,
                                              const int* __restrict__ col, const float* __restrict__ dinv,
                                              const float* __restrict__ bias, const float* __restrict__ Wm,
                                              float* __restrict__ sArr) {
  const int tid = threadIdx.x;
  const int c = tid & 15;                      // 16B chunk within row
  const int v = blockIdx.x * 16 + (tid >> 4);  // grid is exactly N_NODES/16
  const size_t co = (size_t)8 * c;

  float A0[8], A1[8];
  {                                            // self row
    bf16x8 p = *(const bf16x8*)(T3 + (size_t)v * 128 + co);
#pragma unroll
    for (int j = 0; j < 8; ++j) { A0[j] = (float)p[j]; A1[j] = 0.f; }
  }
  int s = rp[v], e = rp[v + 1];
  int i = s;
  for (; i + 4 <= e; i += 4) {
    int u0 = col[i], u1 = col[i + 1], u2 = col[i + 2], u3 = col[i + 3];
    bf16x8 p0 = *(const bf16x8*)(T3 + (size_t)u0 * 128 + co);
    bf16x8 p1 = *(const bf16x8*)(T3 + (size_t)u1 * 128 + co);
    bf16x8 p2 = *(const bf16x8*)(T3 + (size_t)u2 * 128 + co);
    bf16x8 p3 = *(const bf16x8*)(T3 + (size_t)u3 * 128 + co);
#pragma unroll
    for (int j = 0; j < 8; ++j) {
      A0[j] += (float)p0[j] + (float)p2[j];
      A1[j] += (float)p1[j] + (float)p3[j];
    }
  }
  for (; i + 2 <= e; i += 2) {
    int u0 = col[i], u1 = col[i + 1];
    bf16x8 p0 = *(const bf16x8*)(T3 + (size_t)u0 * 128 + co);
    bf16x8 p1 = *(const bf16x8*)(T3 + (size_t)u1 * 128 + co);
#pragma unroll
    for (int j = 0; j < 8; ++j) { A0[j] += (float)p0[j]; A1[j] += (float)p1[j]; }
  }
  if (i < e) {
    bf16x8 p0 = *(const bf16x8*)(T3 + (size_t)col[i] * 128 + co);
#pragma unroll
    for (int j = 0; j < 8; ++j) A0[j] += (float)p0[j];
  }

  float dv = dinv[v];
  float sv = 0.f;
#pragma unroll
  for (int j = 0; j < 8; ++j) {
    int d = (int)co + j;
    float val = fmaxf((A0[j] + A1[j]) * dv + bias[d], 0.f);
    sv += val * Wm[d];
  }
#pragma unroll
  for (int m = 1; m < 16; m <<= 1) sv += __shfl_xor(sv, m);  // reduce within 16-lane group
  if (c == 0) sArr[v] = sv;
}

// ---------------- GEMM (R9 structure — the proven local optimum) ----------------
// R8 journal: BK=32 dbuf pipeline +40us (barrier drains vmcnt(0) anyway).
// R10 journal: A-direct (no A LDS) +43us (A latency lands on MFMA dep chain).
// Keep: A+B staged via global_load_lds, K in 5x64 chunks, 2 barriers/chunk, 8 waves.
// LDS rows 128B, XOR-swizzled via pre-swizzled GLOBAL source; un-swizzled on ds_read.
// EPI 0: H[row][c] = dinv[row]*relu(acc + bias[c])   (bf16, stride KP)
// EPI 1: T3[row][c] = acc                            (bf16, stride NP; input rows carry dinv)

template <int NP, int WM, int WN, int EPI>
__global__ __launch_bounds__(512, 4) void k_gemm(const bf16* __restrict__ A, const bf16* __restrict__ Bt,
                                                 const float* __restrict__ dinv, const float* __restrict__ bias,
                                                 bf16* __restrict__ H) {
  constexpr int WROWS = MT / WM;
  constexpr int MI    = WROWS / 16;
  constexpr int WCOLS = NP / WN;
  constexpr int NC    = WCOLS / 16;
  constexpr int NB_B  = NP / 64;
  __shared__ __attribute__((aligned(16))) char sA[MT * 128];   // 16 KB
  __shared__ __attribute__((aligned(16))) char sB[NP * 128];   // 40/16 KB

  const int tid = threadIdx.x;
  const int w = tid >> 6, l = tid & 63;
  const int wm = w / WN, wn = w % WN;
  const int m0 = blockIdx.x * MT;

  const int sr  = tid >> 3;                      // staging row 0..63 per 64-row group
  const int ssw = ((tid & 7) << 4) ^ ((sr & 7) << 4);
  const char* Ab = (const char*)A;
  const char* Bb = (const char*)Bt;

  const int la = l & 15, q = l >> 4;
  const int msk = (la & 7) << 4;                 // read-side swizzle

  f32x4 acc[MI][NC] = {};

  for (int kh = 0; kh < 5; ++kh) {
#pragma unroll
    for (int i = 0; i < 2; ++i) {
      const char* src = Ab + (size_t)(m0 + i * 64 + sr) * 640 + kh * 128 + ssw;
      __builtin_amdgcn_global_load_lds(AS1(src), AS3(sA + i * 8192 + w * 1024), 16, 0, 0);
    }
#pragma unroll
    for (int i = 0; i < NB_B; ++i) {
      const char* src = Bb + (size_t)(i * 64 + sr) * 640 + kh * 128 + ssw;
      __builtin_amdgcn_global_load_lds(AS1(src), AS3(sB + i * 8192 + w * 1024), 16, 0, 0);
    }
    __syncthreads();

#pragma unroll
    for (int ks = 0; ks < 2; ++ks) {
      const int cb = (ks * 64 + q * 16) ^ msk;
      bf16x8 af[MI];
#pragma unroll
      for (int mi = 0; mi < MI; ++mi) {
        int r = wm * WROWS + mi * 16 + la;
        af[mi] = *(const bf16x8*)(sA + r * 128 + cb);
      }
#pragma unroll
      for (int nc = 0; nc < NC; ++nc) {
        int rb = wn * WCOLS + nc * 16 + la;
        bf16x8 bfr = *(const bf16x8*)(sB + rb * 128 + cb);
#pragma unroll
        for (int mi = 0; mi < MI; ++mi)
          acc[mi][nc] = __builtin_amdgcn_mfma_f32_16x16x32_bf16(af[mi], bfr, acc[mi][nc], 0, 0, 0);
      }
    }
    __syncthreads();
  }

  // C/D layout: col = lane&15, row = (lane>>4)*4 + reg
  const int rbase = m0 + wm * WROWS + q * 4;
  if (EPI == 0) {
    float bc[NC];
#pragma unroll
    for (int nc = 0; nc < NC; ++nc) {
      int c = wn * WCOLS + nc * 16 + la;
      bc[nc] = (c < D_HID) ? bias[c] : 0.f;      // pad cols: acc=0, bias=0 -> stores 0
    }
#pragma unroll
    for (int mi = 0; mi < MI; ++mi) {
#pragma unroll
      for (int r = 0; r < 4; ++r) {
        int row = rbase + mi * 16 + r;
        if (row < N_NODES) {
          float dv = dinv[row];
#pragma unroll
          for (int nc = 0; nc < NC; ++nc) {
            int c = wn * WCOLS + nc * 16 + la;
            H[(size_t)row * KP + c] = (bf16)(fmaxf(acc[mi][nc][r] + bc[nc], 0.f) * dv);
          }
        }
      }
    }
  } else {
#pragma unroll
    for (int mi = 0; mi < MI; ++mi) {
#pragma unroll
      for (int r = 0; r < 4; ++r) {
        int row = rbase + mi * 16 + r;
        if (row < N_NODES) {
#pragma unroll
          for (int nc = 0; nc < NC; ++nc) {
            int c = wn * WCOLS + nc * 16 + la;
            H[(size_t)row * NP + c] = (bf16)acc[mi][nc][r];   // NO dinv: input rows already scaled
          }
        }
      }
    }
  }
}

// ---------------- pooled reduction ----------------

__global__ __launch_bounds__(256) void k_gsum(const float* __restrict__ sArr, const int* __restrict__ batch,
                                              float* __restrict__ gsum, int* __restrict__ cnt) {
  __shared__ float lsum[N_GRAPHS];
  __shared__ int   lcnt[N_GRAPHS];
  int tid = threadIdx.x;
  lsum[tid] = 0.f; lsum[tid + 256] = 0.f;
  lcnt[tid] = 0;   lcnt[tid + 256] = 0;
  __syncthreads();
  int v = blockIdx.x * 256 + tid;
  if (v < N_NODES) {
    int b = batch[v];
    atomicAdd(&lsum[b], sArr[v]);
    atomicAdd(&lcnt[b], 1);
  }
  __syncthreads();
  // sorted batch -> nonzero slots confined to [g0, g1]
  int v0 = blockIdx.x * 256;
  int v1 = min(v0 + 255, N_NODES - 1);
  int g0 = batch[v0], g1 = batch[v1];
  for (int g = g0 + tid; g <= g1; g += 256) {
    int c = lcnt[g];
    if (c) { atomicAdd(&gsum[g], lsum[g]); atomicAdd(&cnt[g], c); }
  }
}

__global__ __launch_bounds__(512) void k_final(const float* __restrict__ gsum, const int* __restrict__ cnt,
                                               const float* __restrict__ bm, float* __restrict__ out) {
  int g = blockIdx.x * 512 + threadIdx.x;
  if (g < N_GRAPHS) out[g] = gsum[g] / fmaxf((float)cnt[g], 1.f) + bm[0];
}

// ---------------- launch ----------------

extern "C" void kernel_launch(void* const* d_in, const int* in_sizes, int n_in,
                              void* d_out, int out_size, void* d_ws, size_t ws_size,
                              hipStream_t stream) {
  const float* x    = (const float*)d_in[0];
  const int*   ei   = (const int*)d_in[1];
  const int*   batch= (const int*)d_in[2];
  const float* W1   = (const float*)d_in[3];
  const float* b1   = (const float*)d_in[4];
  const float* W2   = (const float*)d_in[5];
  const float* b2   = (const float*)d_in[6];
  const float* W3   = (const float*)d_in[7];
  const float* b3   = (const float*)d_in[8];
  const float* Wm   = (const float*)d_in[9];
  const float* bm   = (const float*)d_in[10];
  float* out = (float*)d_out;

  char* ws = (char*)d_ws;
  size_t off = 0;
  auto alloc = [&](size_t bytes) {
    void* p = ws + off;
    off = (off + bytes + 255) & ~(size_t)255;
    return p;
  };
  bf16*  Xs   = (bf16*)alloc((size_t)NPAD * KP * sizeof(bf16));    // 64 MB; reused as H
  bf16*  Ab   = (bf16*)alloc((size_t)NPAD * KP * sizeof(bf16));    // 64 MB
  bf16*  T3   = (bf16*)alloc((size_t)NPAD * 128 * sizeof(bf16));   // 25.6 MB
  bf16*  Wt   = (bf16*)alloc((size_t)3 * KP * KP * sizeof(bf16));  // 614 KB (3 weights)
  int*   deg  = (int*)alloc((size_t)N_NODES * 4);
  float* dinv = (float*)alloc((size_t)N_NODES * 4);
  int*   rp   = (int*)alloc((size_t)(N_NODES + 1) * 4);
  int*   cur  = (int*)alloc((size_t)N_NODES * 4);
  int*   col  = (int*)alloc((size_t)N_EDGES * 4);
  int*   part = (int*)alloc(1024 * 4);
  float* sArr = (float*)alloc((size_t)N_NODES * 4);
  float* gsum = (float*)alloc((size_t)N_GRAPHS * 4);
  int*   cnt  = (int*)alloc((size_t)N_GRAPHS * 4);
  bf16*  H    = Xs;   // Xs dead after layer-1 agg
  bf16*  Wt1  = Wt;
  bf16*  Wt2  = Wt + (size_t)KP * KP;
  bf16*  Wt3  = Wt + (size_t)2 * KP * KP;

  int nbN = (N_NODES + 255) / 256;       // 391
  int nbE4 = (N_EDGES / 4 + 255) / 256;  // 782
  int nbA = (N_NODES + 3) / 4;           // 25000
  int nbWall = (3 * KP * KP + 255) / 256;

  k_init<<<nbN, 256, 0, stream>>>(deg, gsum, cnt);
  k_deg<<<nbE4, 256, 0, stream>>>(ei, deg);
  k_conv_w_all<<<nbWall, 256, 0, stream>>>(W1, W2, W3, Wt);   // off critical chain, one dispatch
  k_scan1<<<nbN, 256, 0, stream>>>(deg, rp, part);
  k_scan2<<<1, 512, 0, stream>>>(part, nbN);
  k_scan3<<<nbN, 256, 0, stream>>>(rp, part, cur, deg, dinv);
  k_fill<<<nbE4, 256, 0, stream>>>(ei, cur, col);
  k_conv_x<<<(N_NODES * (KP / 4) + 255) / 256, 256, 0, stream>>>(x, dinv, Xs);

  // layer 1: aggregate (bf16) -> GEMM (bias+relu+dinv)
  k_aggb<<<nbA, 256, 0, stream>>>(Xs, rp, col, dinv, Ab);
  k_gemm<KP, 2, 4, 0><<<NTILE, 512, 0, stream>>>(Ab, Wt1, dinv, b1, H);
  // layer 2
  k_aggb<<<nbA, 256, 0, stream>>>(H, rp, col, dinv, Ab);
  k_gemm<KP, 2, 4, 0><<<NTILE, 512, 0, stream>>>(Ab, Wt2, dinv, b2, H);
  // layer 3: GEMM first (128-wide; H rows already dinv-scaled), then aggregate + bias + relu + Wm-dot
  k_gemm<128, 8, 1, 1><<<NTILE, 512, 0, stream>>>(H, Wt3, dinv, nullptr, T3);
  k_agg3<<<N_NODES / 16, 256, 0, stream>>>(T3, rp, col, dinv, b3, Wm, sArr);

  k_gsum<<<nbN, 256, 0, stream>>>(sArr, batch, gsum, cnt);
  k_final<<<1, 512, 0, stream>>>(gsum, cnt, bm, out);
}